// Round 1
// baseline (1303.222 us; speedup 1.0000x reference)
//
#include <hip/hip_runtime.h>
#include <math.h>

#define NEG_SLOPE 0.2f

__device__ __forceinline__ float wave_sum(float v){
  #pragma unroll
  for (int o = 1; o < 64; o <<= 1) v += __shfl_xor(v, o, 64);
  return v;
}

// ---------------- edge-weight mean (sum; divide later) ----------------
__global__ void k_sum_ew(const float* __restrict__ ew, int E, float* __restrict__ out){
  float s = 0.f;
  for (int i = blockIdx.x*blockDim.x + threadIdx.x; i < E; i += gridDim.x*blockDim.x) s += ew[i];
  s = wave_sum(s);
  __shared__ float red[4];
  int lane = threadIdx.x & 63, wid = threadIdx.x >> 6;
  if (lane == 0) red[wid] = s;
  __syncthreads();
  if (threadIdx.x == 0){
    float t = 0.f;
    for (int i = 0; i < (int)(blockDim.x >> 6); i++) t += red[i];
    atomicAdd(out, t);
  }
}

// ---------------- degree histogram (dst) ----------------
__global__ void k_deg(const int* __restrict__ dst, int E, int* __restrict__ deg){
  int i = blockIdx.x*blockDim.x + threadIdx.x;
  if (i < E) atomicAdd(&deg[dst[i]], 1);
}

// ---------------- exclusive scan over N nodes (deg+1 each: self loops) ----------------
__global__ __launch_bounds__(1024) void k_scan(const int* __restrict__ deg, int* __restrict__ rowptr,
                                               int* __restrict__ cursor, int n){
  __shared__ int sums[1024];
  int t = threadIdx.x;
  int CH = (n + 1023) >> 10;
  int base = t*CH;
  int local = 0;
  for (int i = 0; i < CH; i++){ int idx = base + i; if (idx < n) local += deg[idx] + 1; }
  sums[t] = local;
  __syncthreads();
  for (int off = 1; off < 1024; off <<= 1){
    int v = (t >= off) ? sums[t-off] : 0;
    __syncthreads();
    sums[t] += v;
    __syncthreads();
  }
  int run = sums[t] - local;   // exclusive prefix
  for (int i = 0; i < CH; i++){
    int idx = base + i;
    if (idx < n){ rowptr[idx] = run; cursor[idx] = run; run += deg[idx] + 1; }
  }
  if (t == 0) rowptr[n] = sums[1023];
}

// ---------------- scatter edges (+ self loops) into CSR ----------------
__global__ void k_scatter(const int* __restrict__ ei, const float* __restrict__ ew, int E, int n,
                          const float* __restrict__ sum_ew, int* __restrict__ cursor,
                          int* __restrict__ csr_src, float* __restrict__ csr_w){
  int i = blockIdx.x*blockDim.x + threadIdx.x;
  if (i >= E + n) return;
  if (i < E){
    int s = ei[i];         // row 0 = src
    int d = ei[E + i];     // row 1 = dst
    int pos = atomicAdd(&cursor[d], 1);
    csr_src[pos] = s; csr_w[pos] = ew[i];
  } else {
    int v = i - E;
    int pos = atomicAdd(&cursor[v], 1);
    csr_src[pos] = v; csr_w[pos] = (*sum_ew) / (float)E;
  }
}

// ---------------- layer-1 linear: x(20000x16) -> xl,xr (20000x512) ----------------
__global__ __launch_bounds__(256) void k_lin1(const float* __restrict__ x,
        const float* __restrict__ Wl, const float* __restrict__ bl,
        const float* __restrict__ Wr, const float* __restrict__ br,
        float* __restrict__ xl, float* __restrict__ xr, int n){
  __shared__ float Ws[16][1028];   // transposed, padded
  __shared__ float bs[1024];
  __shared__ float xs[32][16];
  int t = threadIdx.x;
  for (int i = t; i < 512*16; i += 256){
    int j = i >> 4, k = i & 15;
    Ws[k][j] = Wl[i];
    Ws[k][512 + j] = Wr[i];
  }
  for (int i = t; i < 512; i += 256){ bs[i] = bl[i]; bs[512 + i] = br[i]; }
  int n0 = blockIdx.x * 32;
  for (int i = t; i < 32*16; i += 256){ int r = i >> 4, k = i & 15; xs[r][k] = x[(size_t)(n0 + r)*16 + k]; }
  __syncthreads();
  for (int idx = t; idx < 32*1024; idx += 256){
    int r = idx >> 10, c = idx & 1023;
    float s = bs[c];
    #pragma unroll
    for (int k = 0; k < 16; k++) s += xs[r][k] * Ws[k][c];
    int nn = n0 + r;
    if (c < 512) xl[(size_t)nn*512 + c] = s;
    else         xr[(size_t)nn*512 + (c - 512)] = s;
  }
}

// ---------------- tiled f32 GEMM: out[n][j] = sum_k A[n][k]*W[j][k] + bias[j] ----------------
__global__ __launch_bounds__(256) void k_gemm(const float* __restrict__ A, const float* __restrict__ W,
        const float* __restrict__ bias, float* __restrict__ out, int n, int K, int J){
  __shared__ float As[16][132];   // padded
  __shared__ float Bs[16][68];
  int t = threadIdx.x;
  int tx = t & 15, ty = t >> 4;
  int n0 = blockIdx.y * 128, j0 = blockIdx.x * 64;
  float acc[8][4] = {};
  for (int k0 = 0; k0 < K; k0 += 16){
    #pragma unroll
    for (int i = 0; i < 8; i++){
      int idx = t + i*256; int r = idx >> 4, c = idx & 15;
      int row = n0 + r;
      As[c][r] = (row < n) ? A[(size_t)row*K + k0 + c] : 0.f;
    }
    #pragma unroll
    for (int i = 0; i < 4; i++){
      int idx = t + i*256; int r = idx >> 4, c = idx & 15;
      Bs[c][r] = W[(size_t)(j0 + r)*K + k0 + c];
    }
    __syncthreads();
    #pragma unroll
    for (int kk = 0; kk < 16; kk++){
      float4 b4 = *(const float4*)&Bs[kk][tx*4];
      float4 a0 = *(const float4*)&As[kk][ty*8];
      float4 a1 = *(const float4*)&As[kk][ty*8 + 4];
      float a[8] = {a0.x,a0.y,a0.z,a0.w,a1.x,a1.y,a1.z,a1.w};
      float b[4] = {b4.x,b4.y,b4.z,b4.w};
      #pragma unroll
      for (int u = 0; u < 8; u++)
        #pragma unroll
        for (int v = 0; v < 4; v++)
          acc[u][v] += a[u]*b[v];
    }
    __syncthreads();
  }
  float4 bia = *(const float4*)&bias[j0 + tx*4];
  float bb[4] = {bia.x, bia.y, bia.z, bia.w};
  #pragma unroll
  for (int u = 0; u < 8; u++){
    int row = n0 + ty*8 + u;
    if (row < n){
      float4 o;
      o.x = acc[u][0] + bb[0]; o.y = acc[u][1] + bb[1];
      o.z = acc[u][2] + bb[2]; o.w = acc[u][3] + bb[3];
      *(float4*)&out[(size_t)row*J + j0 + tx*4] = o;
    }
  }
}

// ---------------- GATv2 edge-softmax + aggregation + bias + LayerNorm (+ELU) ----------------
// one block per node; one wave per head; 2 channels per lane
template<int HEADS, bool DO_ELU>
__global__ void k_agg(const float* __restrict__ xl, const float* __restrict__ xr,
                      const float* __restrict__ We, const float* __restrict__ att, const float* __restrict__ bo,
                      const float* __restrict__ gam, const float* __restrict__ bet,
                      const int* __restrict__ rowptr, const int* __restrict__ csr_src,
                      const float* __restrict__ csr_w,
                      float* __restrict__ out, int n){
  constexpr int HC_ = HEADS * 128;
  int nid = blockIdx.x;
  int t = threadIdx.x, lane = t & 63, h = t >> 6;
  int c0 = h*128 + lane*2;
  float2 xr2 = *(const float2*)&xr[(size_t)nid*HC_ + c0];
  float2 we2 = *(const float2*)&We[c0];
  float2 at2 = *(const float2*)&att[c0];
  int rs = rowptr[nid], re = rowptr[nid + 1];
  float m = -3e38f, denom = 0.f, a0 = 0.f, a1 = 0.f;
  for (int e = rs; e < re; ++e){
    int s = csr_src[e];
    float w = csr_w[e];
    float2 xv = *(const float2*)&xl[(size_t)s*HC_ + c0];
    float v0 = xv.x + xr2.x + w*we2.x; v0 = (v0 > 0.f) ? v0 : NEG_SLOPE*v0;
    float v1 = xv.y + xr2.y + w*we2.y; v1 = (v1 > 0.f) ? v1 : NEG_SLOPE*v1;
    float p = wave_sum(v0*at2.x + v1*at2.y);
    float nm = fmaxf(m, p);
    float sc  = __expf(m - nm);
    float wex = __expf(p - nm);
    denom = denom*sc + wex;
    a0 = a0*sc + wex*xv.x;
    a1 = a1*sc + wex*xv.y;
    m = nm;
  }
  float inv = 1.f / (denom + 1e-16f);
  float o0 = a0*inv + bo[c0];
  float o1 = a1*inv + bo[c0 + 1];
  // fused LayerNorm over HC_ channels of this node
  float s1 = o0 + o1, s2 = o0*o0 + o1*o1;
  #pragma unroll
  for (int o = 1; o < 64; o <<= 1){ s1 += __shfl_xor(s1, o, 64); s2 += __shfl_xor(s2, o, 64); }
  __shared__ float red[HEADS][2];
  if (lane == 0){ red[h][0] = s1; red[h][1] = s2; }
  __syncthreads();
  float S1 = 0.f, S2 = 0.f;
  #pragma unroll
  for (int i = 0; i < HEADS; i++){ S1 += red[i][0]; S2 += red[i][1]; }
  float mu = S1 / (float)HC_;
  float var = S2 / (float)HC_ - mu*mu;
  float rstd = rsqrtf(var + 1e-5f);
  float y0 = (o0 - mu)*rstd*gam[c0]   + bet[c0];
  float y1 = (o1 - mu)*rstd*gam[c0+1] + bet[c0+1];
  if (DO_ELU){
    y0 = (y0 > 0.f) ? y0 : expm1f(y0);
    y1 = (y1 > 0.f) ? y1 : expm1f(y1);
  }
  out[(size_t)nid*HC_ + c0]     = y0;
  out[(size_t)nid*HC_ + c0 + 1] = y1;
}

// ---------------- policy/value heads on one node ----------------
__global__ __launch_bounds__(128) void k_heads(const float* __restrict__ h3, const int* __restrict__ idxp,
        const float* __restrict__ Pw1, const float* __restrict__ Pb1,
        const float* __restrict__ Pw2, const float* __restrict__ Pb2,
        const float* __restrict__ Vw1, const float* __restrict__ Vb1,
        const float* __restrict__ Vw2, const float* __restrict__ Vb2,
        float* __restrict__ out){
  __shared__ float z[128], hp[128], hv[128];
  int t = threadIdx.x;
  int idx = *idxp;
  z[t] = h3[(size_t)idx*128 + t];
  __syncthreads();
  float sp = Pb1[t], sv = Vb1[t];
  for (int c = 0; c < 128; c++){
    float zc = z[c];
    sp += Pw1[t*128 + c] * zc;
    sv += Vw1[t*128 + c] * zc;
  }
  hp[t] = fmaxf(sp, 0.f);
  hv[t] = fmaxf(sv, 0.f);
  __syncthreads();
  if (t < 64){
    float l0 = Pw2[t]*hp[t]       + Pw2[64 + t]*hp[64 + t];
    float l1 = Pw2[128 + t]*hp[t] + Pw2[192 + t]*hp[64 + t];
    float vv = Vw2[t]*hv[t]       + Vw2[64 + t]*hv[64 + t];
    #pragma unroll
    for (int o = 1; o < 64; o <<= 1){
      l0 += __shfl_xor(l0, o, 64); l1 += __shfl_xor(l1, o, 64); vv += __shfl_xor(vv, o, 64);
    }
    if (t == 0){ out[0] = l0 + Pb2[0]; out[1] = l1 + Pb2[1]; out[2] = vv + Vb2[0]; }
  }
}

extern "C" void kernel_launch(void* const* d_in, const int* in_sizes, int n_in,
                              void* d_out, int out_size, void* d_ws, size_t ws_size,
                              hipStream_t stream){
  const float* x    = (const float*)d_in[0];
  const int*   ei   = (const int*)d_in[1];
  const float* ew   = (const float*)d_in[2];
  const int*   nidx = (const int*)d_in[3];
  const float* Wl1 = (const float*)d_in[4];  const float* bl1 = (const float*)d_in[5];
  const float* Wr1 = (const float*)d_in[6];  const float* br1 = (const float*)d_in[7];
  const float* We1 = (const float*)d_in[8];  const float* att1 = (const float*)d_in[9];
  const float* bo1 = (const float*)d_in[10];
  const float* Wl2 = (const float*)d_in[11]; const float* bl2 = (const float*)d_in[12];
  const float* Wr2 = (const float*)d_in[13]; const float* br2 = (const float*)d_in[14];
  const float* We2 = (const float*)d_in[15]; const float* att2 = (const float*)d_in[16];
  const float* bo2 = (const float*)d_in[17];
  const float* Wl3 = (const float*)d_in[18]; const float* bl3 = (const float*)d_in[19];
  const float* Wr3 = (const float*)d_in[20]; const float* br3 = (const float*)d_in[21];
  const float* We3 = (const float*)d_in[22]; const float* att3 = (const float*)d_in[23];
  const float* bo3 = (const float*)d_in[24];
  const float* gn1 = (const float*)d_in[25]; const float* bn1 = (const float*)d_in[26];
  const float* gn2 = (const float*)d_in[27]; const float* bn2 = (const float*)d_in[28];
  const float* gn3 = (const float*)d_in[29]; const float* bn3 = (const float*)d_in[30];
  const float* Pw1 = (const float*)d_in[31]; const float* Pb1 = (const float*)d_in[32];
  const float* Pw2 = (const float*)d_in[33]; const float* Pb2 = (const float*)d_in[34];
  const float* Vw1 = (const float*)d_in[35]; const float* Vb1 = (const float*)d_in[36];
  const float* Vw2 = (const float*)d_in[37]; const float* Vb2 = (const float*)d_in[38];

  const int N = in_sizes[0] / 16;
  const int E = in_sizes[2];
  const int NE = N + E;

  char* w = (char*)d_ws;
  size_t off = 0;
  float* sum_ew = (float*)(w + off); off += 256;
  int* rowptr = (int*)(w + off); off += (size_t)(N + 1)*4; off = (off + 255) & ~(size_t)255;
  int* cursor = (int*)(w + off); off += (size_t)N*4;       off = (off + 255) & ~(size_t)255;
  int* deg    = (int*)(w + off); off += (size_t)N*4;       off = (off + 255) & ~(size_t)255;
  int* csr_src= (int*)(w + off); off += (size_t)NE*4;      off = (off + 255) & ~(size_t)255;
  float* csr_w= (float*)(w + off); off += (size_t)NE*4;
  off = (off + 1048575) & ~(size_t)1048575;   // 1MB align for big buffers
  float* A = (float*)(w + off); off += (size_t)N*512*4;
  float* B = (float*)(w + off); off += (size_t)N*512*4;
  float* C = (float*)(w + off); off += (size_t)N*512*4;
  float* D = (float*)(w + off); off += (size_t)N*128*4;
  (void)ws_size; (void)n_in; (void)out_size;

  hipMemsetAsync(sum_ew, 0, 4, stream);
  hipMemsetAsync(deg, 0, (size_t)N*4, stream);

  k_sum_ew<<<256, 256, 0, stream>>>(ew, E, sum_ew);
  k_deg<<<(E + 255)/256, 256, 0, stream>>>(ei + E, E, deg);
  k_scan<<<1, 1024, 0, stream>>>(deg, rowptr, cursor, N);
  k_scatter<<<(NE + 255)/256, 256, 0, stream>>>(ei, ew, E, N, sum_ew, cursor, csr_src, csr_w);

  // Layer 1
  k_lin1<<<N/32, 256, 0, stream>>>(x, Wl1, bl1, Wr1, br1, A, B, N);
  k_agg<4, true><<<N, 256, 0, stream>>>(A, B, We1, att1, bo1, gn1, bn1,
                                        rowptr, csr_src, csr_w, C, N);
  // Layer 2
  {
    dim3 g(512/64, (N + 127)/128);
    k_gemm<<<g, 256, 0, stream>>>(C, Wl2, bl2, A, N, 512, 512);
    k_gemm<<<g, 256, 0, stream>>>(C, Wr2, br2, B, N, 512, 512);
  }
  k_agg<4, true><<<N, 256, 0, stream>>>(A, B, We2, att2, bo2, gn2, bn2,
                                        rowptr, csr_src, csr_w, C, N);
  // Layer 3
  {
    dim3 g(128/64, (N + 127)/128);
    k_gemm<<<g, 256, 0, stream>>>(C, Wl3, bl3, A, N, 512, 128);
    k_gemm<<<g, 256, 0, stream>>>(C, Wr3, br3, B, N, 512, 128);
  }
  k_agg<1, false><<<N, 64, 0, stream>>>(A, B, We3, att3, bo3, gn3, bn3,
                                        rowptr, csr_src, csr_w, D, N);
  // Heads
  k_heads<<<1, 128, 0, stream>>>(D, nidx, Pw1, Pb1, Pw2, Pb2, Vw1, Vb1, Vw2, Vb2, (float*)d_out);
}

// Round 2
// 779.257 us; speedup vs baseline: 1.6724x; 1.6724x over previous
//
#include <hip/hip_runtime.h>
#include <math.h>

#define NEG_SLOPE 0.2f

typedef unsigned short u16;
typedef unsigned int u32;
typedef __attribute__((ext_vector_type(8))) short bf16x8;
typedef __attribute__((ext_vector_type(4))) float f32x4;

__device__ __forceinline__ float wave_sum(float v){
  #pragma unroll
  for (int o = 1; o < 64; o <<= 1) v += __shfl_xor(v, o, 64);
  return v;
}

__device__ __forceinline__ u16 f2bf(float f){
  u32 u = __float_as_uint(f);
  return (u16)((u + 0x7FFF + ((u >> 16) & 1)) >> 16);
}
__device__ __forceinline__ float bf2f(u16 h){
  return __uint_as_float(((u32)h) << 16);
}

__device__ __forceinline__ void gl_lds16(const void* g, void* l){
  __builtin_amdgcn_global_load_lds((const __attribute__((address_space(1))) u32*)g,
                                   (__attribute__((address_space(3))) u32*)l, 16, 0, 0);
}

// ---------------- edge-weight mean (sum; divide later) ----------------
__global__ void k_sum_ew(const float* __restrict__ ew, int E, float* __restrict__ out){
  float s = 0.f;
  for (int i = blockIdx.x*blockDim.x + threadIdx.x; i < E; i += gridDim.x*blockDim.x) s += ew[i];
  s = wave_sum(s);
  __shared__ float red[4];
  int lane = threadIdx.x & 63, wid = threadIdx.x >> 6;
  if (lane == 0) red[wid] = s;
  __syncthreads();
  if (threadIdx.x == 0){
    float t = 0.f;
    for (int i = 0; i < (int)(blockDim.x >> 6); i++) t += red[i];
    atomicAdd(out, t);
  }
}

// ---------------- degree histogram (dst) ----------------
__global__ void k_deg(const int* __restrict__ dst, int E, int* __restrict__ deg){
  int i = blockIdx.x*blockDim.x + threadIdx.x;
  if (i < E) atomicAdd(&deg[dst[i]], 1);
}

// ---------------- exclusive scan over N nodes (deg+1 each: self loops) ----------------
__global__ __launch_bounds__(1024) void k_scan(const int* __restrict__ deg, int* __restrict__ rowptr,
                                               int* __restrict__ cursor, int n){
  __shared__ int sums[1024];
  int t = threadIdx.x;
  int CH = (n + 1023) >> 10;
  int base = t*CH;
  int local = 0;
  for (int i = 0; i < CH; i++){ int idx = base + i; if (idx < n) local += deg[idx] + 1; }
  sums[t] = local;
  __syncthreads();
  for (int off = 1; off < 1024; off <<= 1){
    int v = (t >= off) ? sums[t-off] : 0;
    __syncthreads();
    sums[t] += v;
    __syncthreads();
  }
  int run = sums[t] - local;   // exclusive prefix
  for (int i = 0; i < CH; i++){
    int idx = base + i;
    if (idx < n){ rowptr[idx] = run; cursor[idx] = run; run += deg[idx] + 1; }
  }
  if (t == 0) rowptr[n] = sums[1023];
}

// ---------------- scatter edges (+ self loops) into CSR ----------------
__global__ void k_scatter(const int* __restrict__ ei, const float* __restrict__ ew, int E, int n,
                          const float* __restrict__ sum_ew, int* __restrict__ cursor,
                          int* __restrict__ csr_src, float* __restrict__ csr_w){
  int i = blockIdx.x*blockDim.x + threadIdx.x;
  if (i >= E + n) return;
  if (i < E){
    int s = ei[i];         // row 0 = src
    int d = ei[E + i];     // row 1 = dst
    int pos = atomicAdd(&cursor[d], 1);
    csr_src[pos] = s; csr_w[pos] = ew[i];
  } else {
    int v = i - E;
    int pos = atomicAdd(&cursor[v], 1);
    csr_src[pos] = v; csr_w[pos] = (*sum_ew) / (float)E;
  }
}

// ---------------- split f32 -> bf16 hi/lo planes ----------------
__global__ void k_split(const float* __restrict__ in, u16* __restrict__ hi, u16* __restrict__ lo, int m){
  for (int i = blockIdx.x*blockDim.x + threadIdx.x; i < m; i += gridDim.x*blockDim.x){
    float a = in[i];
    u16 h = f2bf(a);
    hi[i] = h;
    lo[i] = f2bf(a - bf2f(h));
  }
}

// ---------------- layer-1 linear: x(Nx16) -> xl,xr (Nx512) ----------------
__global__ __launch_bounds__(256) void k_lin1(const float* __restrict__ x,
        const float* __restrict__ Wl, const float* __restrict__ bl,
        const float* __restrict__ Wr, const float* __restrict__ br,
        float* __restrict__ xl, float* __restrict__ xr, int n){
  __shared__ float Ws[16][1028];   // transposed, padded
  __shared__ float bs[1024];
  __shared__ float xs[32][16];
  int t = threadIdx.x;
  for (int i = t; i < 512*16; i += 256){
    int j = i >> 4, k = i & 15;
    Ws[k][j] = Wl[i];
    Ws[k][512 + j] = Wr[i];
  }
  for (int i = t; i < 512; i += 256){ bs[i] = bl[i]; bs[512 + i] = br[i]; }
  int n0 = blockIdx.x * 32;
  for (int i = t; i < 32*16; i += 256){ int r = i >> 4, k = i & 15; xs[r][k] = x[(size_t)(n0 + r)*16 + k]; }
  __syncthreads();
  for (int idx = t; idx < 32*1024; idx += 256){
    int r = idx >> 10, c = idx & 1023;
    float s = bs[c];
    #pragma unroll
    for (int k = 0; k < 16; k++) s += xs[r][k] * Ws[k][c];
    int nn = n0 + r;
    if (c < 512) xl[(size_t)nn*512 + c] = s;
    else         xr[(size_t)nn*512 + (c - 512)] = s;
  }
}

// ---------------- split-bf16 MFMA GEMM: out[n][j] = sum_k A[n][k]*W[j][k] + bias[j] ----------------
// A given as hi/lo bf16 planes [n][K]; W as hi/lo planes [J][K]. BM=BN=128, BK=32.
// LDS layout per plane: [128 rows][32 bf16 = 64B], 16B slots XOR-swizzled:
//   lds_byte(r, c16) = r*64 + (c16*16 ^ (((r>>1)&3)<<4))
// Staging keeps LDS dest linear (global_load_lds) and applies the inverse XOR to the
// per-lane global source (rule: both-sides-or-neither).
__global__ __launch_bounds__(256,2) void k_gemm_mfma(
    const u16* __restrict__ Ah, const u16* __restrict__ Al,
    const u16* __restrict__ Wh, const u16* __restrict__ Wl,
    const float* __restrict__ bias, float* __restrict__ out,
    int n, int K, int J){
  __shared__ __align__(16) u16 lds[16384];   // 32KB: Ah,Al,Wh,Wl planes of 4096 u16
  u16* lA_h = lds;
  u16* lA_l = lds + 4096;
  u16* lW_h = lds + 8192;
  u16* lW_l = lds + 12288;
  int t = threadIdx.x;
  int lane = t & 63, w = t >> 6;
  int lane15 = lane & 15, lgrp = lane >> 4;
  int n0 = blockIdx.y * 128, j0 = blockIdx.x * 128;
  int wm = (w >> 1) * 64, wn = (w & 1) * 64;
  f32x4 acc[4][4] = {};

  // staging constants: plane has 512 16B slots; thread handles slots t and t+256
  int s0 = t, s1 = t + 256;
  int r0 = s0 >> 2, r1 = s1 >> 2;
  int sl0 = (s0 & 3) ^ ((r0 >> 1) & 3);
  int sl1 = (s1 & 3) ^ ((r1 >> 1) & 3);
  size_t arow0 = (size_t)min(n0 + r0, n - 1) * K + sl0*8;
  size_t arow1 = (size_t)min(n0 + r1, n - 1) * K + sl1*8;
  size_t wrow0 = (size_t)(j0 + r0) * K + sl0*8;
  size_t wrow1 = (size_t)(j0 + r1) * K + sl1*8;

  // reader constants: byte col within a row (swizzled)
  int rcol = (lgrp * 16) ^ (((lane15 >> 1) & 3) << 4);

  for (int k0 = 0; k0 < K; k0 += 32){
    gl_lds16(Ah + arow0 + k0, lA_h + s0*8);
    gl_lds16(Ah + arow1 + k0, lA_h + s1*8);
    gl_lds16(Al + arow0 + k0, lA_l + s0*8);
    gl_lds16(Al + arow1 + k0, lA_l + s1*8);
    gl_lds16(Wh + wrow0 + k0, lW_h + s0*8);
    gl_lds16(Wh + wrow1 + k0, lW_h + s1*8);
    gl_lds16(Wl + wrow0 + k0, lW_l + s0*8);
    gl_lds16(Wl + wrow1 + k0, lW_l + s1*8);
    __syncthreads();
    bf16x8 ah[4], al[4], bh[4], bl_[4];
    #pragma unroll
    for (int i = 0; i < 4; i++){
      int qa = (wm + i*16 + lane15)*64 + rcol;
      ah[i]  = *(const bf16x8*)((const char*)lA_h + qa);
      al[i]  = *(const bf16x8*)((const char*)lA_l + qa);
      int qb = (wn + i*16 + lane15)*64 + rcol;
      bh[i]  = *(const bf16x8*)((const char*)lW_h + qb);
      bl_[i] = *(const bf16x8*)((const char*)lW_l + qb);
    }
    #pragma unroll
    for (int mi = 0; mi < 4; mi++)
      #pragma unroll
      for (int ni = 0; ni < 4; ni++){
        acc[mi][ni] = __builtin_amdgcn_mfma_f32_16x16x32_bf16(ah[mi], bh[ni],  acc[mi][ni], 0, 0, 0);
        acc[mi][ni] = __builtin_amdgcn_mfma_f32_16x16x32_bf16(ah[mi], bl_[ni], acc[mi][ni], 0, 0, 0);
        acc[mi][ni] = __builtin_amdgcn_mfma_f32_16x16x32_bf16(al[mi], bh[ni],  acc[mi][ni], 0, 0, 0);
      }
    __syncthreads();
  }

  #pragma unroll
  for (int ni = 0; ni < 4; ni++){
    int col = j0 + wn + ni*16 + lane15;
    float bia = bias[col];
    #pragma unroll
    for (int mi = 0; mi < 4; mi++){
      int rowb = n0 + wm + mi*16 + lgrp*4;
      #pragma unroll
      for (int rg = 0; rg < 4; rg++){
        int row = rowb + rg;
        if (row < n) out[(size_t)row*J + col] = acc[mi][ni][rg] + bia;
      }
    }
  }
}

// ---------------- GATv2 edge-softmax + aggregation + bias + LayerNorm (+ELU) ----------------
// one block per node; one wave per head; 2 channels per lane
template<int HEADS, bool DO_ELU, bool EMIT>
__global__ void k_agg(const float* __restrict__ xl, const float* __restrict__ xr,
                      const float* __restrict__ We, const float* __restrict__ att, const float* __restrict__ bo,
                      const float* __restrict__ gam, const float* __restrict__ bet,
                      const int* __restrict__ rowptr, const int* __restrict__ csr_src,
                      const float* __restrict__ csr_w,
                      float* __restrict__ out, u16* __restrict__ oh, u16* __restrict__ ol, int n){
  constexpr int HC_ = HEADS * 128;
  int nid = blockIdx.x;
  int t = threadIdx.x, lane = t & 63, h = t >> 6;
  int c0 = h*128 + lane*2;
  float2 xr2 = *(const float2*)&xr[(size_t)nid*HC_ + c0];
  float2 we2 = *(const float2*)&We[c0];
  float2 at2 = *(const float2*)&att[c0];
  int rs = rowptr[nid], re = rowptr[nid + 1];
  float m = -3e38f, denom = 0.f, a0 = 0.f, a1 = 0.f;
  for (int e = rs; e < re; ++e){
    int s = csr_src[e];
    float w = csr_w[e];
    float2 xv = *(const float2*)&xl[(size_t)s*HC_ + c0];
    float v0 = xv.x + xr2.x + w*we2.x; v0 = (v0 > 0.f) ? v0 : NEG_SLOPE*v0;
    float v1 = xv.y + xr2.y + w*we2.y; v1 = (v1 > 0.f) ? v1 : NEG_SLOPE*v1;
    float p = wave_sum(v0*at2.x + v1*at2.y);
    float nm = fmaxf(m, p);
    float sc  = __expf(m - nm);
    float wex = __expf(p - nm);
    denom = denom*sc + wex;
    a0 = a0*sc + wex*xv.x;
    a1 = a1*sc + wex*xv.y;
    m = nm;
  }
  float inv = 1.f / (denom + 1e-16f);
  float o0 = a0*inv + bo[c0];
  float o1 = a1*inv + bo[c0 + 1];
  // fused LayerNorm over HC_ channels of this node
  float s1 = o0 + o1, s2 = o0*o0 + o1*o1;
  #pragma unroll
  for (int o = 1; o < 64; o <<= 1){ s1 += __shfl_xor(s1, o, 64); s2 += __shfl_xor(s2, o, 64); }
  __shared__ float red[HEADS][2];
  if (lane == 0){ red[h][0] = s1; red[h][1] = s2; }
  __syncthreads();
  float S1 = 0.f, S2 = 0.f;
  #pragma unroll
  for (int i = 0; i < HEADS; i++){ S1 += red[i][0]; S2 += red[i][1]; }
  float mu = S1 / (float)HC_;
  float var = S2 / (float)HC_ - mu*mu;
  float rstd = rsqrtf(var + 1e-5f);
  float y0 = (o0 - mu)*rstd*gam[c0]   + bet[c0];
  float y1 = (o1 - mu)*rstd*gam[c0+1] + bet[c0+1];
  if (DO_ELU){
    y0 = (y0 > 0.f) ? y0 : expm1f(y0);
    y1 = (y1 > 0.f) ? y1 : expm1f(y1);
  }
  if (EMIT){
    u16 h0 = f2bf(y0), h1 = f2bf(y1);
    u16 l0 = f2bf(y0 - bf2f(h0)), l1 = f2bf(y1 - bf2f(h1));
    *(u32*)&oh[(size_t)nid*HC_ + c0] = (u32)h0 | ((u32)h1 << 16);
    *(u32*)&ol[(size_t)nid*HC_ + c0] = (u32)l0 | ((u32)l1 << 16);
  } else {
    out[(size_t)nid*HC_ + c0]     = y0;
    out[(size_t)nid*HC_ + c0 + 1] = y1;
  }
}

// ---------------- policy/value heads on one node ----------------
__global__ __launch_bounds__(128) void k_heads(const float* __restrict__ h3, const int* __restrict__ idxp,
        const float* __restrict__ Pw1, const float* __restrict__ Pb1,
        const float* __restrict__ Pw2, const float* __restrict__ Pb2,
        const float* __restrict__ Vw1, const float* __restrict__ Vb1,
        const float* __restrict__ Vw2, const float* __restrict__ Vb2,
        float* __restrict__ out){
  __shared__ float z[128], hp[128], hv[128];
  int t = threadIdx.x;
  int idx = *idxp;
  z[t] = h3[(size_t)idx*128 + t];
  __syncthreads();
  float sp = Pb1[t], sv = Vb1[t];
  for (int c = 0; c < 128; c++){
    float zc = z[c];
    sp += Pw1[t*128 + c] * zc;
    sv += Vw1[t*128 + c] * zc;
  }
  hp[t] = fmaxf(sp, 0.f);
  hv[t] = fmaxf(sv, 0.f);
  __syncthreads();
  if (t < 64){
    float l0 = Pw2[t]*hp[t]       + Pw2[64 + t]*hp[64 + t];
    float l1 = Pw2[128 + t]*hp[t] + Pw2[192 + t]*hp[64 + t];
    float vv = Vw2[t]*hv[t]       + Vw2[64 + t]*hv[64 + t];
    #pragma unroll
    for (int o = 1; o < 64; o <<= 1){
      l0 += __shfl_xor(l0, o, 64); l1 += __shfl_xor(l1, o, 64); vv += __shfl_xor(vv, o, 64);
    }
    if (t == 0){ out[0] = l0 + Pb2[0]; out[1] = l1 + Pb2[1]; out[2] = vv + Vb2[0]; }
  }
}

extern "C" void kernel_launch(void* const* d_in, const int* in_sizes, int n_in,
                              void* d_out, int out_size, void* d_ws, size_t ws_size,
                              hipStream_t stream){
  const float* x    = (const float*)d_in[0];
  const int*   ei   = (const int*)d_in[1];
  const float* ew   = (const float*)d_in[2];
  const int*   nidx = (const int*)d_in[3];
  const float* Wl1 = (const float*)d_in[4];  const float* bl1 = (const float*)d_in[5];
  const float* Wr1 = (const float*)d_in[6];  const float* br1 = (const float*)d_in[7];
  const float* We1 = (const float*)d_in[8];  const float* att1 = (const float*)d_in[9];
  const float* bo1 = (const float*)d_in[10];
  const float* Wl2 = (const float*)d_in[11]; const float* bl2 = (const float*)d_in[12];
  const float* Wr2 = (const float*)d_in[13]; const float* br2 = (const float*)d_in[14];
  const float* We2 = (const float*)d_in[15]; const float* att2 = (const float*)d_in[16];
  const float* bo2 = (const float*)d_in[17];
  const float* Wl3 = (const float*)d_in[18]; const float* bl3 = (const float*)d_in[19];
  const float* Wr3 = (const float*)d_in[20]; const float* br3 = (const float*)d_in[21];
  const float* We3 = (const float*)d_in[22]; const float* att3 = (const float*)d_in[23];
  const float* bo3 = (const float*)d_in[24];
  const float* gn1 = (const float*)d_in[25]; const float* bn1 = (const float*)d_in[26];
  const float* gn2 = (const float*)d_in[27]; const float* bn2 = (const float*)d_in[28];
  const float* gn3 = (const float*)d_in[29]; const float* bn3 = (const float*)d_in[30];
  const float* Pw1 = (const float*)d_in[31]; const float* Pb1 = (const float*)d_in[32];
  const float* Pw2 = (const float*)d_in[33]; const float* Pb2 = (const float*)d_in[34];
  const float* Vw1 = (const float*)d_in[35]; const float* Vb1 = (const float*)d_in[36];
  const float* Vw2 = (const float*)d_in[37]; const float* Vb2 = (const float*)d_in[38];

  const int N = in_sizes[0] / 16;
  const int E = in_sizes[2];
  const int NE = N + E;

  char* w = (char*)d_ws;
  size_t off = 0;
  float* sum_ew = (float*)(w + off); off += 256;
  int* rowptr = (int*)(w + off); off += (size_t)(N + 1)*4; off = (off + 255) & ~(size_t)255;
  int* cursor = (int*)(w + off); off += (size_t)N*4;       off = (off + 255) & ~(size_t)255;
  int* deg    = (int*)(w + off); off += (size_t)N*4;       off = (off + 255) & ~(size_t)255;
  int* csr_src= (int*)(w + off); off += (size_t)NE*4;      off = (off + 255) & ~(size_t)255;
  float* csr_w= (float*)(w + off); off += (size_t)NE*4;    off = (off + 255) & ~(size_t)255;
  // weight bf16 hi/lo planes
  u16* W2lh = (u16*)(w + off); off += (size_t)512*512*2;
  u16* W2ll = (u16*)(w + off); off += (size_t)512*512*2;
  u16* W2rh = (u16*)(w + off); off += (size_t)512*512*2;
  u16* W2rl = (u16*)(w + off); off += (size_t)512*512*2;
  u16* W3lh = (u16*)(w + off); off += (size_t)128*512*2;
  u16* W3ll = (u16*)(w + off); off += (size_t)128*512*2;
  u16* W3rh = (u16*)(w + off); off += (size_t)128*512*2;
  u16* W3rl = (u16*)(w + off); off += (size_t)128*512*2;
  off = (off + 1048575) & ~(size_t)1048575;   // 1MB align for big buffers
  float* A  = (float*)(w + off); off += (size_t)N*512*4;
  float* B  = (float*)(w + off); off += (size_t)N*512*4;
  u16*   Ch = (u16*)(w + off);   off += (size_t)N*512*2;
  u16*   Cl = (u16*)(w + off);   off += (size_t)N*512*2;
  float* D  = (float*)Ch;        // D [N][128] f32 aliases Ch (Ch dead after layer-3 GEMMs)
  (void)ws_size; (void)n_in; (void)out_size;

  hipMemsetAsync(sum_ew, 0, 4, stream);
  hipMemsetAsync(deg, 0, (size_t)N*4, stream);

  k_sum_ew<<<256, 256, 0, stream>>>(ew, E, sum_ew);
  k_deg<<<(E + 255)/256, 256, 0, stream>>>(ei + E, E, deg);
  k_scan<<<1, 1024, 0, stream>>>(deg, rowptr, cursor, N);
  k_scatter<<<(NE + 255)/256, 256, 0, stream>>>(ei, ew, E, N, sum_ew, cursor, csr_src, csr_w);

  // weight splits (small)
  k_split<<<128, 256, 0, stream>>>(Wl2, W2lh, W2ll, 512*512);
  k_split<<<128, 256, 0, stream>>>(Wr2, W2rh, W2rl, 512*512);
  k_split<<<64, 256, 0, stream>>>(Wl3, W3lh, W3ll, 128*512);
  k_split<<<64, 256, 0, stream>>>(Wr3, W3rh, W3rl, 128*512);

  const int GY = (N + 127)/128;

  // Layer 1
  k_lin1<<<N/32, 256, 0, stream>>>(x, Wl1, bl1, Wr1, br1, A, B, N);
  k_agg<4, true, true><<<N, 256, 0, stream>>>(A, B, We1, att1, bo1, gn1, bn1,
                                              rowptr, csr_src, csr_w, nullptr, Ch, Cl, N);
  // Layer 2
  k_gemm_mfma<<<dim3(4, GY), 256, 0, stream>>>(Ch, Cl, W2lh, W2ll, bl2, A, N, 512, 512);
  k_gemm_mfma<<<dim3(4, GY), 256, 0, stream>>>(Ch, Cl, W2rh, W2rl, br2, B, N, 512, 512);
  k_agg<4, true, true><<<N, 256, 0, stream>>>(A, B, We2, att2, bo2, gn2, bn2,
                                              rowptr, csr_src, csr_w, nullptr, Ch, Cl, N);
  // Layer 3
  k_gemm_mfma<<<dim3(1, GY), 256, 0, stream>>>(Ch, Cl, W3lh, W3ll, bl3, A, N, 512, 128);
  k_gemm_mfma<<<dim3(1, GY), 256, 0, stream>>>(Ch, Cl, W3rh, W3rl, br3, B, N, 512, 128);
  k_agg<1, false, false><<<N, 64, 0, stream>>>(A, B, We3, att3, bo3, gn3, bn3,
                                               rowptr, csr_src, csr_w, D, nullptr, nullptr, N);
  // Heads
  k_heads<<<1, 128, 0, stream>>>(D, nidx, Pw1, Pb1, Pw2, Pb2, Vw1, Vb1, Vw2, Vb2, (float*)d_out);
}

// Round 3
// 745.652 us; speedup vs baseline: 1.7478x; 1.0451x over previous
//
#include <hip/hip_runtime.h>
#include <math.h>

#define NEG_SLOPE 0.2f

typedef unsigned short u16;
typedef unsigned int u32;
typedef __attribute__((ext_vector_type(8))) short bf16x8;
typedef __attribute__((ext_vector_type(4))) float f32x4;

__device__ __forceinline__ float wave_sum(float v){
  #pragma unroll
  for (int o = 1; o < 64; o <<= 1) v += __shfl_xor(v, o, 64);
  return v;
}

__device__ __forceinline__ u16 f2bf(float f){
  u32 u = __float_as_uint(f);
  return (u16)((u + 0x7FFF + ((u >> 16) & 1)) >> 16);
}
__device__ __forceinline__ float bf2f(u16 h){
  return __uint_as_float(((u32)h) << 16);
}

__device__ __forceinline__ void gl_lds16(const void* g, void* l){
  __builtin_amdgcn_global_load_lds((const __attribute__((address_space(1))) u32*)g,
                                   (__attribute__((address_space(3))) u32*)l, 16, 0, 0);
}

// ---------------- edge-weight mean (sum; divide later) ----------------
__global__ void k_sum_ew(const float* __restrict__ ew, int E, float* __restrict__ out){
  float s = 0.f;
  for (int i = blockIdx.x*blockDim.x + threadIdx.x; i < E; i += gridDim.x*blockDim.x) s += ew[i];
  s = wave_sum(s);
  __shared__ float red[4];
  int lane = threadIdx.x & 63, wid = threadIdx.x >> 6;
  if (lane == 0) red[wid] = s;
  __syncthreads();
  if (threadIdx.x == 0){
    float t = 0.f;
    for (int i = 0; i < (int)(blockDim.x >> 6); i++) t += red[i];
    atomicAdd(out, t);
  }
}

// ---------------- degree histogram (dst) ----------------
__global__ void k_deg(const int* __restrict__ dst, int E, int* __restrict__ deg){
  int i = blockIdx.x*blockDim.x + threadIdx.x;
  if (i < E) atomicAdd(&deg[dst[i]], 1);
}

// ---------------- exclusive scan over N nodes (deg+1 each: self loops) ----------------
__global__ __launch_bounds__(1024) void k_scan(const int* __restrict__ deg, int* __restrict__ rowptr,
                                               int* __restrict__ cursor, int n){
  __shared__ int sums[1024];
  int t = threadIdx.x;
  int CH = (n + 1023) >> 10;
  int base = t*CH;
  int local = 0;
  for (int i = 0; i < CH; i++){ int idx = base + i; if (idx < n) local += deg[idx] + 1; }
  sums[t] = local;
  __syncthreads();
  for (int off = 1; off < 1024; off <<= 1){
    int v = (t >= off) ? sums[t-off] : 0;
    __syncthreads();
    sums[t] += v;
    __syncthreads();
  }
  int run = sums[t] - local;   // exclusive prefix
  for (int i = 0; i < CH; i++){
    int idx = base + i;
    if (idx < n){ rowptr[idx] = run; cursor[idx] = run; run += deg[idx] + 1; }
  }
  if (t == 0) rowptr[n] = sums[1023];
}

// ---------------- scatter edges (+ self loops) into CSR ----------------
__global__ void k_scatter(const int* __restrict__ ei, const float* __restrict__ ew, int E, int n,
                          const float* __restrict__ sum_ew, int* __restrict__ cursor,
                          int* __restrict__ csr_src, float* __restrict__ csr_w){
  int i = blockIdx.x*blockDim.x + threadIdx.x;
  if (i >= E + n) return;
  if (i < E){
    int s = ei[i];         // row 0 = src
    int d = ei[E + i];     // row 1 = dst
    int pos = atomicAdd(&cursor[d], 1);
    csr_src[pos] = s; csr_w[pos] = ew[i];
  } else {
    int v = i - E;
    int pos = atomicAdd(&cursor[v], 1);
    csr_src[pos] = v; csr_w[pos] = (*sum_ew) / (float)E;
  }
}

// ---------------- split f32 -> bf16 hi/lo planes ----------------
__global__ void k_split(const float* __restrict__ in, u16* __restrict__ hi, u16* __restrict__ lo, int m){
  for (int i = blockIdx.x*blockDim.x + threadIdx.x; i < m; i += gridDim.x*blockDim.x){
    float a = in[i];
    u16 h = f2bf(a);
    hi[i] = h;
    lo[i] = f2bf(a - bf2f(h));
  }
}

// ---------------- layer-1 linear: x(Nx16) -> xl,xr (Nx512) ----------------
__global__ __launch_bounds__(256) void k_lin1(const float* __restrict__ x,
        const float* __restrict__ Wl, const float* __restrict__ bl,
        const float* __restrict__ Wr, const float* __restrict__ br,
        float* __restrict__ xl, float* __restrict__ xr, int n){
  __shared__ float Ws[16][1028];   // transposed, padded
  __shared__ float bs[1024];
  __shared__ float xs[32][16];
  int t = threadIdx.x;
  for (int i = t; i < 512*16; i += 256){
    int j = i >> 4, k = i & 15;
    Ws[k][j] = Wl[i];
    Ws[k][512 + j] = Wr[i];
  }
  for (int i = t; i < 512; i += 256){ bs[i] = bl[i]; bs[512 + i] = br[i]; }
  int n0 = blockIdx.x * 32;
  for (int i = t; i < 32*16; i += 256){ int r = i >> 4, k = i & 15; xs[r][k] = x[(size_t)(n0 + r)*16 + k]; }
  __syncthreads();
  for (int idx = t; idx < 32*1024; idx += 256){
    int r = idx >> 10, c = idx & 1023;
    float s = bs[c];
    #pragma unroll
    for (int k = 0; k < 16; k++) s += xs[r][k] * Ws[k][c];
    int nn = n0 + r;
    if (c < 512) xl[(size_t)nn*512 + c] = s;
    else         xr[(size_t)nn*512 + (c - 512)] = s;
  }
}

// ---------------- split-bf16 MFMA GEMM ----------------
__global__ __launch_bounds__(256,2) void k_gemm_mfma(
    const u16* __restrict__ Ah, const u16* __restrict__ Al,
    const u16* __restrict__ Wh, const u16* __restrict__ Wl,
    const float* __restrict__ bias, float* __restrict__ out,
    int n, int K, int J){
  __shared__ __align__(16) u16 lds[16384];   // 32KB: Ah,Al,Wh,Wl planes of 4096 u16
  u16* lA_h = lds;
  u16* lA_l = lds + 4096;
  u16* lW_h = lds + 8192;
  u16* lW_l = lds + 12288;
  int t = threadIdx.x;
  int lane = t & 63, w = t >> 6;
  int lane15 = lane & 15, lgrp = lane >> 4;
  int n0 = blockIdx.y * 128, j0 = blockIdx.x * 128;
  int wm = (w >> 1) * 64, wn = (w & 1) * 64;
  f32x4 acc[4][4] = {};

  int s0 = t, s1 = t + 256;
  int r0 = s0 >> 2, r1 = s1 >> 2;
  int sl0 = (s0 & 3) ^ ((r0 >> 1) & 3);
  int sl1 = (s1 & 3) ^ ((r1 >> 1) & 3);
  size_t arow0 = (size_t)min(n0 + r0, n - 1) * K + sl0*8;
  size_t arow1 = (size_t)min(n0 + r1, n - 1) * K + sl1*8;
  size_t wrow0 = (size_t)(j0 + r0) * K + sl0*8;
  size_t wrow1 = (size_t)(j0 + r1) * K + sl1*8;

  int rcol = (lgrp * 16) ^ (((lane15 >> 1) & 3) << 4);

  for (int k0 = 0; k0 < K; k0 += 32){
    gl_lds16(Ah + arow0 + k0, lA_h + s0*8);
    gl_lds16(Ah + arow1 + k0, lA_h + s1*8);
    gl_lds16(Al + arow0 + k0, lA_l + s0*8);
    gl_lds16(Al + arow1 + k0, lA_l + s1*8);
    gl_lds16(Wh + wrow0 + k0, lW_h + s0*8);
    gl_lds16(Wh + wrow1 + k0, lW_h + s1*8);
    gl_lds16(Wl + wrow0 + k0, lW_l + s0*8);
    gl_lds16(Wl + wrow1 + k0, lW_l + s1*8);
    __syncthreads();
    bf16x8 ah[4], al[4], bh[4], bl_[4];
    #pragma unroll
    for (int i = 0; i < 4; i++){
      int qa = (wm + i*16 + lane15)*64 + rcol;
      ah[i]  = *(const bf16x8*)((const char*)lA_h + qa);
      al[i]  = *(const bf16x8*)((const char*)lA_l + qa);
      int qb = (wn + i*16 + lane15)*64 + rcol;
      bh[i]  = *(const bf16x8*)((const char*)lW_h + qb);
      bl_[i] = *(const bf16x8*)((const char*)lW_l + qb);
    }
    #pragma unroll
    for (int mi = 0; mi < 4; mi++)
      #pragma unroll
      for (int ni = 0; ni < 4; ni++){
        acc[mi][ni] = __builtin_amdgcn_mfma_f32_16x16x32_bf16(ah[mi], bh[ni],  acc[mi][ni], 0, 0, 0);
        acc[mi][ni] = __builtin_amdgcn_mfma_f32_16x16x32_bf16(ah[mi], bl_[ni], acc[mi][ni], 0, 0, 0);
        acc[mi][ni] = __builtin_amdgcn_mfma_f32_16x16x32_bf16(al[mi], bh[ni],  acc[mi][ni], 0, 0, 0);
      }
    __syncthreads();
  }

  #pragma unroll
  for (int ni = 0; ni < 4; ni++){
    int col = j0 + wn + ni*16 + lane15;
    float bia = bias[col];
    #pragma unroll
    for (int mi = 0; mi < 4; mi++){
      int rowb = n0 + wm + mi*16 + lgrp*4;
      #pragma unroll
      for (int rg = 0; rg < 4; rg++){
        int row = rowb + rg;
        if (row < n) out[(size_t)row*J + col] = acc[mi][ni][rg] + bia;
      }
    }
  }
}

// ---------------- GATv2 edge-softmax + aggregation + bias + LayerNorm (+ELU) ----------------
// one block per node; one wave per head; within a wave: 4 groups x 16 lanes,
// each group owns one edge at a time, 8 channels per lane (float4 x2 loads).
template<int HEADS, bool DO_ELU, bool EMIT>
__global__ void k_agg(const float* __restrict__ xl, const float* __restrict__ xr,
                      const float* __restrict__ We, const float* __restrict__ att, const float* __restrict__ bo,
                      const float* __restrict__ gam, const float* __restrict__ bet,
                      const int* __restrict__ rowptr, const int* __restrict__ csr_src,
                      const float* __restrict__ csr_w,
                      float* __restrict__ out, u16* __restrict__ oh, u16* __restrict__ ol, int n){
  constexpr int HC_ = HEADS * 128;
  int nid = blockIdx.x;
  int t = threadIdx.x, lane = t & 63, h = t >> 6;
  int l16 = lane & 15, lgrp = lane >> 4;
  int c0 = h*128 + l16*8;          // 8 channels per lane

  const float* xr_row = xr + (size_t)nid*HC_ + c0;
  float4 xra = *(const float4*)xr_row, xrb = *(const float4*)(xr_row + 4);
  float4 wea = *(const float4*)&We[c0], web = *(const float4*)&We[c0 + 4];
  float4 ata = *(const float4*)&att[c0], atb = *(const float4*)&att[c0 + 4];
  float xr8[8] = {xra.x,xra.y,xra.z,xra.w,xrb.x,xrb.y,xrb.z,xrb.w};
  float we8[8] = {wea.x,wea.y,wea.z,wea.w,web.x,web.y,web.z,web.w};
  float at8[8] = {ata.x,ata.y,ata.z,ata.w,atb.x,atb.y,atb.z,atb.w};

  int rs = rowptr[nid], re = rowptr[nid + 1];
  float m = -3e38f, d = 0.f;
  float acc[8] = {};
  for (int e = rs + lgrp; e < re; e += 4){
    int s = csr_src[e];
    float w = csr_w[e];
    const float* row = xl + (size_t)s*HC_ + c0;
    float4 v0 = *(const float4*)row;
    float4 v1 = *(const float4*)(row + 4);
    float v[8] = {v0.x,v0.y,v0.z,v0.w,v1.x,v1.y,v1.z,v1.w};
    float p = 0.f;
    #pragma unroll
    for (int j = 0; j < 8; j++){
      float tv = v[j] + xr8[j] + w*we8[j];
      tv = (tv > 0.f) ? tv : NEG_SLOPE*tv;
      p += tv * at8[j];
    }
    // 16-lane group reduce (xor masks 1,2,4,8 stay within group)
    #pragma unroll
    for (int o = 1; o < 16; o <<= 1) p += __shfl_xor(p, o, 64);
    float nm = fmaxf(m, p);
    float sc  = __expf(m - nm);
    float wex = __expf(p - nm);
    d = d*sc + wex;
    #pragma unroll
    for (int j = 0; j < 8; j++) acc[j] = acc[j]*sc + wex*v[j];
    m = nm;
  }
  // merge the 4 groups' online states (xor masks 16, 32)
  float M = m;
  M = fmaxf(M, __shfl_xor(M, 16, 64));
  M = fmaxf(M, __shfl_xor(M, 32, 64));
  float sc = __expf(m - M);
  float dd = d * sc;
  dd += __shfl_xor(dd, 16, 64);
  dd += __shfl_xor(dd, 32, 64);
  #pragma unroll
  for (int j = 0; j < 8; j++){
    float a = acc[j] * sc;
    a += __shfl_xor(a, 16, 64);
    a += __shfl_xor(a, 32, 64);
    acc[j] = a;
  }
  float inv = 1.f / (dd + 1e-16f);
  float o8[8];
  #pragma unroll
  for (int j = 0; j < 8; j++) o8[j] = acc[j]*inv + bo[c0 + j];

  // LayerNorm over HC_ channels
  float s1 = 0.f, s2 = 0.f;
  #pragma unroll
  for (int j = 0; j < 8; j++){ s1 += o8[j]; s2 += o8[j]*o8[j]; }
  #pragma unroll
  for (int o = 1; o < 16; o <<= 1){ s1 += __shfl_xor(s1, o, 64); s2 += __shfl_xor(s2, o, 64); }
  float S1, S2;
  if (HEADS == 4){
    __shared__ float red[4][2];
    if (lane == 0){ red[h][0] = s1; red[h][1] = s2; }
    __syncthreads();
    S1 = red[0][0] + red[1][0] + red[2][0] + red[3][0];
    S2 = red[0][1] + red[1][1] + red[2][1] + red[3][1];
  } else {
    S1 = s1; S2 = s2;
  }
  float mu = S1 / (float)HC_;
  float var = S2 / (float)HC_ - mu*mu;
  float rstd = rsqrtf(var + 1e-5f);
  float4 ga = *(const float4*)&gam[c0], gb = *(const float4*)&gam[c0 + 4];
  float4 ba = *(const float4*)&bet[c0], bb = *(const float4*)&bet[c0 + 4];
  float g8[8] = {ga.x,ga.y,ga.z,ga.w,gb.x,gb.y,gb.z,gb.w};
  float b8[8] = {ba.x,ba.y,ba.z,ba.w,bb.x,bb.y,bb.z,bb.w};
  float y[8];
  #pragma unroll
  for (int j = 0; j < 8; j++){
    float yy = (o8[j] - mu)*rstd*g8[j] + b8[j];
    if (DO_ELU) yy = (yy > 0.f) ? yy : expm1f(yy);
    y[j] = yy;
  }
  if (lgrp == 0){
    if (EMIT){
      u32 hv[4], lv[4];
      #pragma unroll
      for (int j = 0; j < 4; j++){
        u16 h0 = f2bf(y[2*j]), h1 = f2bf(y[2*j+1]);
        u16 l0 = f2bf(y[2*j] - bf2f(h0)), l1 = f2bf(y[2*j+1] - bf2f(h1));
        hv[j] = (u32)h0 | ((u32)h1 << 16);
        lv[j] = (u32)l0 | ((u32)l1 << 16);
      }
      *(uint4*)&oh[(size_t)nid*HC_ + c0] = make_uint4(hv[0],hv[1],hv[2],hv[3]);
      *(uint4*)&ol[(size_t)nid*HC_ + c0] = make_uint4(lv[0],lv[1],lv[2],lv[3]);
    } else {
      float* orow = out + (size_t)nid*HC_ + c0;
      *(float4*)orow       = make_float4(y[0],y[1],y[2],y[3]);
      *(float4*)(orow + 4) = make_float4(y[4],y[5],y[6],y[7]);
    }
  }
}

// ---------------- policy/value heads on one node ----------------
__global__ __launch_bounds__(128) void k_heads(const float* __restrict__ h3, const int* __restrict__ idxp,
        const float* __restrict__ Pw1, const float* __restrict__ Pb1,
        const float* __restrict__ Pw2, const float* __restrict__ Pb2,
        const float* __restrict__ Vw1, const float* __restrict__ Vb1,
        const float* __restrict__ Vw2, const float* __restrict__ Vb2,
        float* __restrict__ out){
  __shared__ float z[128], hp[128], hv[128];
  int t = threadIdx.x;
  int idx = *idxp;
  z[t] = h3[(size_t)idx*128 + t];
  __syncthreads();
  float sp = Pb1[t], sv = Vb1[t];
  for (int c = 0; c < 128; c++){
    float zc = z[c];
    sp += Pw1[t*128 + c] * zc;
    sv += Vw1[t*128 + c] * zc;
  }
  hp[t] = fmaxf(sp, 0.f);
  hv[t] = fmaxf(sv, 0.f);
  __syncthreads();
  if (t < 64){
    float l0 = Pw2[t]*hp[t]       + Pw2[64 + t]*hp[64 + t];
    float l1 = Pw2[128 + t]*hp[t] + Pw2[192 + t]*hp[64 + t];
    float vv = Vw2[t]*hv[t]       + Vw2[64 + t]*hv[64 + t];
    #pragma unroll
    for (int o = 1; o < 64; o <<= 1){
      l0 += __shfl_xor(l0, o, 64); l1 += __shfl_xor(l1, o, 64); vv += __shfl_xor(vv, o, 64);
    }
    if (t == 0){ out[0] = l0 + Pb2[0]; out[1] = l1 + Pb2[1]; out[2] = vv + Vb2[0]; }
  }
}

extern "C" void kernel_launch(void* const* d_in, const int* in_sizes, int n_in,
                              void* d_out, int out_size, void* d_ws, size_t ws_size,
                              hipStream_t stream){
  const float* x    = (const float*)d_in[0];
  const int*   ei   = (const int*)d_in[1];
  const float* ew   = (const float*)d_in[2];
  const int*   nidx = (const int*)d_in[3];
  const float* Wl1 = (const float*)d_in[4];  const float* bl1 = (const float*)d_in[5];
  const float* Wr1 = (const float*)d_in[6];  const float* br1 = (const float*)d_in[7];
  const float* We1 = (const float*)d_in[8];  const float* att1 = (const float*)d_in[9];
  const float* bo1 = (const float*)d_in[10];
  const float* Wl2 = (const float*)d_in[11]; const float* bl2 = (const float*)d_in[12];
  const float* Wr2 = (const float*)d_in[13]; const float* br2 = (const float*)d_in[14];
  const float* We2 = (const float*)d_in[15]; const float* att2 = (const float*)d_in[16];
  const float* bo2 = (const float*)d_in[17];
  const float* Wl3 = (const float*)d_in[18]; const float* bl3 = (const float*)d_in[19];
  const float* Wr3 = (const float*)d_in[20]; const float* br3 = (const float*)d_in[21];
  const float* We3 = (const float*)d_in[22]; const float* att3 = (const float*)d_in[23];
  const float* bo3 = (const float*)d_in[24];
  const float* gn1 = (const float*)d_in[25]; const float* bn1 = (const float*)d_in[26];
  const float* gn2 = (const float*)d_in[27]; const float* bn2 = (const float*)d_in[28];
  const float* gn3 = (const float*)d_in[29]; const float* bn3 = (const float*)d_in[30];
  const float* Pw1 = (const float*)d_in[31]; const float* Pb1 = (const float*)d_in[32];
  const float* Pw2 = (const float*)d_in[33]; const float* Pb2 = (const float*)d_in[34];
  const float* Vw1 = (const float*)d_in[35]; const float* Vb1 = (const float*)d_in[36];
  const float* Vw2 = (const float*)d_in[37]; const float* Vb2 = (const float*)d_in[38];

  const int N = in_sizes[0] / 16;
  const int E = in_sizes[2];
  const int NE = N + E;

  char* w = (char*)d_ws;
  size_t off = 0;
  float* sum_ew = (float*)(w + off); off += 256;
  int* rowptr = (int*)(w + off); off += (size_t)(N + 1)*4; off = (off + 255) & ~(size_t)255;
  int* cursor = (int*)(w + off); off += (size_t)N*4;       off = (off + 255) & ~(size_t)255;
  int* deg    = (int*)(w + off); off += (size_t)N*4;       off = (off + 255) & ~(size_t)255;
  int* csr_src= (int*)(w + off); off += (size_t)NE*4;      off = (off + 255) & ~(size_t)255;
  float* csr_w= (float*)(w + off); off += (size_t)NE*4;    off = (off + 255) & ~(size_t)255;
  // weight bf16 hi/lo planes
  u16* W2lh = (u16*)(w + off); off += (size_t)512*512*2;
  u16* W2ll = (u16*)(w + off); off += (size_t)512*512*2;
  u16* W2rh = (u16*)(w + off); off += (size_t)512*512*2;
  u16* W2rl = (u16*)(w + off); off += (size_t)512*512*2;
  u16* W3lh = (u16*)(w + off); off += (size_t)128*512*2;
  u16* W3ll = (u16*)(w + off); off += (size_t)128*512*2;
  u16* W3rh = (u16*)(w + off); off += (size_t)128*512*2;
  u16* W3rl = (u16*)(w + off); off += (size_t)128*512*2;
  off = (off + 1048575) & ~(size_t)1048575;   // 1MB align for big buffers
  float* A  = (float*)(w + off); off += (size_t)N*512*4;
  float* B  = (float*)(w + off); off += (size_t)N*512*4;
  u16*   Ch = (u16*)(w + off);   off += (size_t)N*512*2;
  u16*   Cl = (u16*)(w + off);   off += (size_t)N*512*2;
  float* D  = (float*)Ch;        // D [N][128] f32 aliases Ch (Ch dead after layer-3 GEMMs)
  (void)ws_size; (void)n_in; (void)out_size;

  hipMemsetAsync(sum_ew, 0, 4, stream);
  hipMemsetAsync(deg, 0, (size_t)N*4, stream);

  k_sum_ew<<<256, 256, 0, stream>>>(ew, E, sum_ew);
  k_deg<<<(E + 255)/256, 256, 0, stream>>>(ei + E, E, deg);
  k_scan<<<1, 1024, 0, stream>>>(deg, rowptr, cursor, N);
  k_scatter<<<(NE + 255)/256, 256, 0, stream>>>(ei, ew, E, N, sum_ew, cursor, csr_src, csr_w);

  // weight splits (small)
  k_split<<<128, 256, 0, stream>>>(Wl2, W2lh, W2ll, 512*512);
  k_split<<<128, 256, 0, stream>>>(Wr2, W2rh, W2rl, 512*512);
  k_split<<<64, 256, 0, stream>>>(Wl3, W3lh, W3ll, 128*512);
  k_split<<<64, 256, 0, stream>>>(Wr3, W3rh, W3rl, 128*512);

  const int GY = (N + 127)/128;

  // Layer 1
  k_lin1<<<N/32, 256, 0, stream>>>(x, Wl1, bl1, Wr1, br1, A, B, N);
  k_agg<4, true, true><<<N, 256, 0, stream>>>(A, B, We1, att1, bo1, gn1, bn1,
                                              rowptr, csr_src, csr_w, nullptr, Ch, Cl, N);
  // Layer 2
  k_gemm_mfma<<<dim3(4, GY), 256, 0, stream>>>(Ch, Cl, W2lh, W2ll, bl2, A, N, 512, 512);
  k_gemm_mfma<<<dim3(4, GY), 256, 0, stream>>>(Ch, Cl, W2rh, W2rl, br2, B, N, 512, 512);
  k_agg<4, true, true><<<N, 256, 0, stream>>>(A, B, We2, att2, bo2, gn2, bn2,
                                              rowptr, csr_src, csr_w, nullptr, Ch, Cl, N);
  // Layer 3
  k_gemm_mfma<<<dim3(1, GY), 256, 0, stream>>>(Ch, Cl, W3lh, W3ll, bl3, A, N, 512, 128);
  k_gemm_mfma<<<dim3(1, GY), 256, 0, stream>>>(Ch, Cl, W3rh, W3rl, br3, B, N, 512, 128);
  k_agg<1, false, false><<<N, 64, 0, stream>>>(A, B, We3, att3, bo3, gn3, bn3,
                                               rowptr, csr_src, csr_w, D, nullptr, nullptr, N);
  // Heads
  k_heads<<<1, 128, 0, stream>>>(D, nidx, Pw1, Pb1, Pw2, Pb2, Vw1, Vb1, Vw2, Vb2, (float*)d_out);
}